// Round 1
// baseline (2322.009 us; speedup 1.0000x reference)
//
#include <hip/hip_runtime.h>
#include <hip/hip_bf16.h>

#define F 64
#define NB 8
#define SDIM 9
#define NE 10
#define GSEG 4

__device__ __forceinline__ float silu(float x) {
    return x / (1.0f + __expf(-x));
}

// ---------------------------------------------------------------------------
// Kernel 1: per-node init. scal0[n][g] = sum_e attrs[n][e]*W_embed[e][g];
// energy[batch[n]] += attrs[n] . atomic_energies
// one wave per node, lane = feature g
// ---------------------------------------------------------------------------
__global__ __launch_bounds__(256) void init_nodes(
    const float* __restrict__ node_attrs, const float* __restrict__ AE,
    const float* __restrict__ W_embed, const int* __restrict__ batch,
    float* __restrict__ scal, float* __restrict__ energy, int N)
{
    int w = threadIdx.x >> 6, g = threadIdx.x & 63;
    int n = blockIdx.x * 4 + w;
    __shared__ float bins[GSEG];
    if (threadIdx.x < GSEG) bins[threadIdx.x] = 0.0f;
    __syncthreads();
    if (n < N) {
        float sc = 0.0f, e0 = 0.0f;
        #pragma unroll
        for (int e = 0; e < NE; e++) {
            float a = node_attrs[n * NE + e];
            sc = fmaf(a, W_embed[e * F + g], sc);
            e0 = fmaf(a, AE[e], e0);
        }
        scal[(size_t)n * F + g] = sc;
        if (g == 0) atomicAdd(&bins[batch[n]], e0);
    }
    __syncthreads();
    if (threadIdx.x < GSEG) {
        float bv = bins[threadIdx.x];
        if (bv != 0.0f) atomicAdd(&energy[threadIdx.x], bv);
    }
}

// ---------------------------------------------------------------------------
// Kernel 2: edge compaction. Keep only edges with r < R_MAX (envelope != 0).
// ---------------------------------------------------------------------------
__global__ __launch_bounds__(256) void edge_prep(
    const float* __restrict__ pos, const float* __restrict__ shifts,
    const int* __restrict__ EI, int E,
    int* __restrict__ count, float4* __restrict__ act_f4, int2* __restrict__ act_sd)
{
    int e = blockIdx.x * 256 + threadIdx.x;
    if (e >= E) return;
    int s = EI[e], d = EI[E + e];
    float vx = pos[d * 3 + 0] - pos[s * 3 + 0] + shifts[e * 3 + 0];
    float vy = pos[d * 3 + 1] - pos[s * 3 + 1] + shifts[e * 3 + 1];
    float vz = pos[d * 3 + 2] - pos[s * 3 + 2] + shifts[e * 3 + 2];
    float len = sqrtf(vx * vx + vy * vy + vz * vz);
    if (len < 5.0f) {
        float ls = (len > 1e-6f) ? len : 1.0f;
        float inv = 1.0f / ls;
        int idx = atomicAdd(count, 1);   // compiler wave-aggregates
        act_f4[idx] = make_float4(vx * inv, vy * inv, vz * inv, len);
        act_sd[idx] = make_int2(s, d);
    }
}

// ---------------------------------------------------------------------------
// Kernel 3: per-active-edge radial MLP + message scatter.
// One thread per active edge. Weights are wave-uniform -> scalar loads.
// ---------------------------------------------------------------------------
__global__ __launch_bounds__(256) void edge_mlp(
    const float* __restrict__ Wr0, const float* __restrict__ Wr1,
    const float* __restrict__ Wr2,
    const float* __restrict__ scal, const int* __restrict__ count,
    const float4* __restrict__ act_f4, const int2* __restrict__ act_sd,
    float* __restrict__ A)
{
    int idx = blockIdx.x * 256 + threadIdx.x;
    if (idx >= *count) return;
    float4 gv = act_f4[idx];
    int2 sd = act_sd[idx];
    float ux = gv.x, uy = gv.y, uz = gv.z, r = gv.w;

    // radial embedding: bessel * polynomial cutoff (r < 5 guaranteed)
    float rs = fmaxf(r, 1e-6f);
    float th = 0.6283185307179586f * rs;   // pi * r / 5
    float s1, c1;
    __sincosf(th, &s1, &c1);
    float u = r * 0.2f;
    float u2 = u * u, u4 = u2 * u2, u5 = u4 * u, u6 = u5 * u, u7 = u6 * u;
    float fc = 1.0f - 21.0f * u5 + 35.0f * u6 - 15.0f * u7;
    float pref = 0.6324555320336759f / rs * fc;  // sqrt(2/5)
    float ef[NB];
    {
        float sprev = 0.0f, scur = s1, twoc = 2.0f * c1;
        #pragma unroll
        for (int k = 0; k < NB; k++) {
            ef[k] = pref * scur;
            float snext = twoc * scur - sprev;
            sprev = scur; scur = snext;
        }
    }

    // spherical harmonics
    const float s3 = 1.7320508075688772f;
    const float s5h = 1.1180339887498948f;
    const float s15 = 3.8729833462074170f;
    const float s15h = 1.9364916731037085f;
    float Y1 = s3 * ux, Y2 = s3 * uy, Y3 = s3 * uz;
    float Y4 = s15 * ux * uy, Y5 = s15 * uy * uz;
    float Y6 = s5h * (3.0f * uz * uz - 1.0f);
    float Y7 = s15 * ux * uz;
    float Y8 = s15h * (ux * ux - uy * uy);

    // layer 1: 8 -> 64, silu
    float h1[64];
    #pragma unroll
    for (int j = 0; j < 64; j++) {
        float acc = 0.0f;
        #pragma unroll
        for (int k = 0; k < NB; k++) acc = fmaf(ef[k], Wr0[k * 64 + j], acc);
        h1[j] = silu(acc);
    }
    // layer 2: 64 -> 64, silu
    float h2[64];
    #pragma unroll
    for (int j = 0; j < 64; j++) {
        float acc = 0.0f;
        #pragma unroll
        for (int k = 0; k < 64; k++) acc = fmaf(h1[k], Wr1[k * 64 + j], acc);
        h2[j] = silu(acc);
    }

    // layer 3: 64 -> 192 (per f: 3 outputs), fused with message scatter
    const float* sp = scal + (size_t)sd.x * F;
    float* Abase = A + (size_t)sd.y * (F * SDIM);
    for (int f = 0; f < 64; f++) {
        float w0 = 0.0f, w1 = 0.0f, w2 = 0.0f;
        #pragma unroll
        for (int k = 0; k < 64; k++) {
            float hk = h2[k];
            const float* wr = Wr2 + k * 192 + f * 3;
            w0 = fmaf(hk, wr[0], w0);
            w1 = fmaf(hk, wr[1], w1);
            w2 = fmaf(hk, wr[2], w2);
        }
        float sv = sp[f];
        float m0 = w0 * sv, m1 = w1 * sv, m2 = w2 * sv;
        float* ab = Abase + f * SDIM;
        atomicAdd(ab + 0, m0);
        atomicAdd(ab + 1, m1 * Y1);
        atomicAdd(ab + 2, m1 * Y2);
        atomicAdd(ab + 3, m1 * Y3);
        atomicAdd(ab + 4, m2 * Y4);
        atomicAdd(ab + 5, m2 * Y5);
        atomicAdd(ab + 6, m2 * Y6);
        atomicAdd(ab + 7, m2 * Y7);
        atomicAdd(ab + 8, m2 * Y8);
    }
}

// ---------------------------------------------------------------------------
// Kernel 4: per-node mixing + polynomial scaling + energy readout.
// One wave per node, lane = output feature g.
// PHASE 0: write new scal, energy += scal @ Wread0
// PHASE 1: residual add, energy += silu(scal @ Wm1) @ wm2
// ---------------------------------------------------------------------------
template <int PHASE>
__global__ __launch_bounds__(256) void node_kernel(
    const float* __restrict__ A, const float* __restrict__ Wmix_t,
    const float* __restrict__ Wprod_t, const float* __restrict__ node_attrs,
    const int* __restrict__ batch,
    const float* __restrict__ Wread0, const float* __restrict__ Wm1,
    const float* __restrict__ wm2,
    float* __restrict__ scal, float* __restrict__ energy, int N)
{
    int w = threadIdx.x >> 6, g = threadIdx.x & 63;
    int n = blockIdx.x * 4 + w;
    __shared__ float bins[GSEG];
    __shared__ float lsc[4][64];
    if (threadIdx.x < GSEG) bins[threadIdx.x] = 0.0f;
    __syncthreads();

    bool active = (n < N);
    float sc0 = 0.0f;
    int b = 0;
    if (active) {
        const float* Ar = A + (size_t)n * (F * SDIM);
        float am[SDIM];
        #pragma unroll
        for (int s = 0; s < SDIM; s++) am[s] = 0.0f;
        for (int f = 0; f < F; f++) {
            float w0 = Wmix_t[f * 64 + g];
            float w1 = Wmix_t[4096 + f * 64 + g];
            float w2 = Wmix_t[8192 + f * 64 + g];
            const float* a = Ar + f * SDIM;   // wave-uniform -> scalar loads
            am[0] = fmaf(a[0], w0, am[0]);
            am[1] = fmaf(a[1], w1, am[1]);
            am[2] = fmaf(a[2], w1, am[2]);
            am[3] = fmaf(a[3], w1, am[3]);
            am[4] = fmaf(a[4], w2, am[4]);
            am[5] = fmaf(a[5], w2, am[5]);
            am[6] = fmaf(a[6], w2, am[6]);
            am[7] = fmaf(a[7], w2, am[7]);
            am[8] = fmaf(a[8], w2, am[8]);
        }
        #pragma unroll
        for (int s = 0; s < SDIM; s++) am[s] *= 0.0625f;   // / AVG_NEIGH

        float wp0 = 0.0f, wp1 = 0.0f, wp2 = 0.0f;
        #pragma unroll
        for (int e = 0; e < NE; e++) {
            float a = node_attrs[n * NE + e];
            const float* W = Wprod_t + (e * F + g) * 3;
            wp0 = fmaf(a, W[0], wp0);
            wp1 = fmaf(a, W[1], wp1);
            wp2 = fmaf(a, W[2], wp2);
        }
        float p1 = am[0];
        float p2 = 0.0f;
        #pragma unroll
        for (int s = 0; s < SDIM; s++) p2 = fmaf(am[s], am[s], p2);
        float scale = wp0 + wp1 * p1 + wp2 * p2;
        sc0 = am[0] * scale;
        b = batch[n];
    }

    if (PHASE == 0) {
        if (active) {
            scal[(size_t)n * F + g] = sc0;
            float v = sc0 * Wread0[g];
            #pragma unroll
            for (int off = 32; off > 0; off >>= 1) v += __shfl_xor(v, off);
            if (g == 0) atomicAdd(&bins[b], v);
        }
    } else {
        if (active) {
            sc0 += scal[(size_t)n * F + g];   // residual (prev channel-0)
            lsc[w][g] = sc0;
        } else {
            lsc[w][g] = 0.0f;
        }
        __syncthreads();
        if (active) {
            float v = 0.0f;
            if (g < 16) {
                float acc = 0.0f;
                for (int k = 0; k < 64; k++)
                    acc = fmaf(lsc[w][k], Wm1[k * 16 + g], acc);
                v = silu(acc) * wm2[g];
            }
            #pragma unroll
            for (int off = 32; off > 0; off >>= 1) v += __shfl_xor(v, off);
            if (g == 0) atomicAdd(&bins[b], v);
        }
    }
    __syncthreads();
    if (threadIdx.x < GSEG) {
        float bv = bins[threadIdx.x];
        if (bv != 0.0f) atomicAdd(&energy[threadIdx.x], bv);
    }
}

extern "C" void kernel_launch(void* const* d_in, const int* in_sizes, int n_in,
                              void* d_out, int out_size, void* d_ws, size_t ws_size,
                              hipStream_t stream) {
    const float* positions  = (const float*)d_in[0];
    const float* node_attrs = (const float*)d_in[1];
    const float* shifts     = (const float*)d_in[2];
    // d_in[3] charges: unused (charge_density never feeds energy)
    const int*   edge_index = (const int*)d_in[4];
    const int*   batch      = (const int*)d_in[5];
    const float* AE         = (const float*)d_in[6];
    const float* W_embed    = (const float*)d_in[7];
    const float* Wr0        = (const float*)d_in[8];
    const float* Wr1        = (const float*)d_in[9];
    const float* Wr2        = (const float*)d_in[10];
    const float* Wmix       = (const float*)d_in[11];
    const float* Wprod      = (const float*)d_in[12];
    const float* Wread0     = (const float*)d_in[13];
    const float* Wm1        = (const float*)d_in[14];
    const float* wm2        = (const float*)d_in[15];
    // d_in[16] Wq: unused

    int N = in_sizes[0] / 3;
    int E = in_sizes[4] / 2;
    float* out = (float*)d_out;

    char* ws = (char*)d_ws;
    size_t Abytes = (size_t)N * F * SDIM * sizeof(float);   // 46.08 MB
    float*  A      = (float*)ws;
    float*  scal   = (float*)(ws + Abytes);
    size_t off = Abytes + (size_t)N * F * sizeof(float);
    int*    count  = (int*)(ws + off);   off += 256;
    float4* act_f4 = (float4*)(ws + off); off += (size_t)E * sizeof(float4);
    int2*   act_sd = (int2*)(ws + off);   off += (size_t)E * sizeof(int2);

    hipMemsetAsync(d_out, 0, GSEG * sizeof(float), stream);
    hipMemsetAsync(count, 0, sizeof(int), stream);
    hipMemsetAsync(A, 0, Abytes, stream);

    int nodeBlocks = (N + 3) / 4;
    int edgeBlocks = (E + 255) / 256;

    init_nodes<<<nodeBlocks, 256, 0, stream>>>(node_attrs, AE, W_embed, batch, scal, out, N);
    edge_prep<<<edgeBlocks, 256, 0, stream>>>(positions, shifts, edge_index, E, count, act_f4, act_sd);

    // t = 0
    edge_mlp<<<edgeBlocks, 256, 0, stream>>>(Wr0, Wr1, Wr2, scal, count, act_f4, act_sd, A);
    node_kernel<0><<<nodeBlocks, 256, 0, stream>>>(A, Wmix, Wprod, node_attrs, batch,
                                                   Wread0, Wm1, wm2, scal, out, N);
    // t = 1
    hipMemsetAsync(A, 0, Abytes, stream);
    edge_mlp<<<edgeBlocks, 256, 0, stream>>>(Wr0 + 512, Wr1 + 4096, Wr2 + 12288,
                                             scal, count, act_f4, act_sd, A);
    node_kernel<1><<<nodeBlocks, 256, 0, stream>>>(A, Wmix + 3 * 4096, Wprod + NE * F * 3,
                                                   node_attrs, batch,
                                                   Wread0, Wm1, wm2, scal, out, N);
}

// Round 2
// 663.110 us; speedup vs baseline: 3.5017x; 3.5017x over previous
//
#include <hip/hip_runtime.h>
#include <hip/hip_bf16.h>

#define F 64
#define NB 8
#define NE 10
#define GSEG 4
#define EPW 256   // energy-partial spread width (contention relief)

__device__ __forceinline__ float silu(float x) {
    return x / (1.0f + __expf(-x));
}

// ---------------------------------------------------------------------------
// Kernel 1: per-node init. S0[n][g] = attrs[n] @ W_embed; e0 -> epart.
// one wave per node, lane = feature g
// ---------------------------------------------------------------------------
__global__ __launch_bounds__(256) void init_nodes(
    const float* __restrict__ node_attrs, const float* __restrict__ AE,
    const float* __restrict__ W_embed, const int* __restrict__ batch,
    float* __restrict__ S0, float* __restrict__ epart, int N)
{
    int w = threadIdx.x >> 6, g = threadIdx.x & 63;
    int n = blockIdx.x * 4 + w;
    if (n >= N) return;
    float sc = 0.0f, e0 = 0.0f;
    #pragma unroll
    for (int e = 0; e < NE; e++) {
        float a = node_attrs[n * NE + e];
        sc = fmaf(a, W_embed[e * F + g], sc);
        e0 = fmaf(a, AE[e], e0);
    }
    S0[(size_t)n * F + g] = sc;
    if (g == 0) atomicAdd(&epart[batch[n] * EPW + (n & (EPW - 1))], e0);
}

// ---------------------------------------------------------------------------
// Kernel 2: edge compaction (r < R_MAX) + per-dst degree count.
// ---------------------------------------------------------------------------
__global__ __launch_bounds__(256) void edge_prep(
    const float* __restrict__ pos, const float* __restrict__ shifts,
    const int* __restrict__ EI, int E,
    int* __restrict__ count, float4* __restrict__ geo,
    int* __restrict__ esrc, int* __restrict__ edst, int* __restrict__ deg)
{
    int e = blockIdx.x * 256 + threadIdx.x;
    if (e >= E) return;
    int s = EI[e], d = EI[E + e];
    float vx = pos[d * 3 + 0] - pos[s * 3 + 0] + shifts[e * 3 + 0];
    float vy = pos[d * 3 + 1] - pos[s * 3 + 1] + shifts[e * 3 + 1];
    float vz = pos[d * 3 + 2] - pos[s * 3 + 2] + shifts[e * 3 + 2];
    float len = sqrtf(vx * vx + vy * vy + vz * vz);
    if (len < 5.0f) {
        float ls = (len > 1e-6f) ? len : 1.0f;
        float inv = 1.0f / ls;
        int idx = atomicAdd(count, 1);   // compiler wave-aggregates
        geo[idx] = make_float4(vx * inv, vy * inv, vz * inv, len);
        esrc[idx] = s;
        edst[idx] = d;
        atomicAdd(&deg[d], 1);
    }
}

// ---------------------------------------------------------------------------
// Kernel 3: allocate contiguous CSR ranges (order across nodes irrelevant).
// ---------------------------------------------------------------------------
__global__ __launch_bounds__(256) void alloc_start(
    const int* __restrict__ deg, int* __restrict__ start,
    int* __restrict__ cursor, int* __restrict__ total, int N)
{
    int n = blockIdx.x * 256 + threadIdx.x;
    if (n >= N) return;
    int st = atomicAdd(total, deg[n]);
    start[n] = st;
    cursor[n] = st;
}

// ---------------------------------------------------------------------------
// Kernel 4: scatter compact-edge ids into per-dst CSR slots.
// ---------------------------------------------------------------------------
__global__ __launch_bounds__(256) void scatter_perm(
    const int* __restrict__ count, const int* __restrict__ edst,
    int* __restrict__ cursor, int* __restrict__ perm)
{
    int i = blockIdx.x * 256 + threadIdx.x;
    if (i >= *count) return;
    int p = atomicAdd(&cursor[edst[i]], 1);
    perm[p] = i;
}

// ---------------------------------------------------------------------------
// Kernel 5: fused per-node gather. One wave (block=64) per dst node.
// For each incoming edge: radial MLP (lanes cooperate via LDS, h in LDS
// not spilled regs), message accumulated in 9 registers. Then Wmix mixing
// via LDS transpose, polynomial scale, energy readout. A never hits global.
// PHASE 0: write Sout, energy += sc0 @ Wread0
// PHASE 1: residual, energy += silu(sc @ Wm1) @ wm2
// ---------------------------------------------------------------------------
template <int PHASE>
__global__ __launch_bounds__(64) void gather_node(
    const float4* __restrict__ geo, const int* __restrict__ esrc,
    const int* __restrict__ perm, const int* __restrict__ start,
    const int* __restrict__ deg,
    const float* __restrict__ Wr0t, const float* __restrict__ Wr1t,
    const float* __restrict__ Wr2t, const float* __restrict__ Wmixt,
    const float* __restrict__ Wprodt,
    const float* __restrict__ node_attrs, const int* __restrict__ batch,
    const float* __restrict__ Wread0, const float* __restrict__ Wm1,
    const float* __restrict__ wm2,
    const float* __restrict__ Sin, float* __restrict__ Sout,
    float* __restrict__ epart, int N)
{
    int g = threadIdx.x;            // lane = feature f (and output g later)
    int n = blockIdx.x;
    __shared__ float h1s[64];
    __shared__ float h2s[64];
    __shared__ float At[64 * 12];   // 12-float stride: 16B-aligned float4 rows
    __shared__ float scs[64];

    int st = start[n], dg = deg[n];
    float am0 = 0.f, am1 = 0.f, am2_ = 0.f, am3 = 0.f, am4 = 0.f,
          am5 = 0.f, am6 = 0.f, am7 = 0.f, am8 = 0.f;

    for (int i = 0; i < dg; i++) {
        int e = perm[st + i];
        float4 gv = geo[e];          // wave-uniform
        int srcn = esrc[e];
        float ux = gv.x, uy = gv.y, uz = gv.z, r = gv.w;

        // radial embedding (uniform across lanes; cheap)
        float rs = fmaxf(r, 1e-6f);
        float s1, c1;
        __sincosf(0.6283185307179586f * rs, &s1, &c1);   // pi*r/5
        float u = r * 0.2f;
        float u2 = u * u, u4 = u2 * u2, u5 = u4 * u, u6 = u5 * u, u7 = u6 * u;
        float fc = 1.0f - 21.0f * u5 + 35.0f * u6 - 15.0f * u7;
        float pref = 0.6324555320336759f / rs * fc;      // sqrt(2/5)
        float ef[NB];
        {
            float sp = 0.0f, sc_ = s1, tc = 2.0f * c1;
            #pragma unroll
            for (int k = 0; k < NB; k++) {
                ef[k] = pref * sc_;
                float sn = tc * sc_ - sp;
                sp = sc_; sc_ = sn;
            }
        }

        // layer 1: 8 -> 64 (lane j computes h1[j])
        float a1 = 0.0f;
        #pragma unroll
        for (int k = 0; k < NB; k++) a1 = fmaf(ef[k], Wr0t[k * 64 + g], a1);
        h1s[g] = silu(a1);
        __syncthreads();            // block = 1 wave: convergent, cheap

        // layer 2: 64 -> 64
        float a2 = 0.0f;
        for (int k = 0; k < 64; k++) a2 = fmaf(h1s[k], Wr1t[k * 64 + g], a2);
        h2s[g] = silu(a2);
        __syncthreads();

        // layer 3: lane f computes w[f][0..2]
        float w0 = 0.f, w1 = 0.f, w2 = 0.f;
        for (int k = 0; k < 64; k++) {
            float hk = h2s[k];
            const float* wr = Wr2t + k * 192 + g * 3;
            w0 = fmaf(hk, wr[0], w0);
            w1 = fmaf(hk, wr[1], w1);
            w2 = fmaf(hk, wr[2], w2);
        }
        __syncthreads();

        // message accumulate (registers only)
        float sv = Sin[(size_t)srcn * F + g];
        float m0 = w0 * sv, m1 = w1 * sv, m2 = w2 * sv;
        const float s3 = 1.7320508075688772f;
        const float s5h = 1.1180339887498948f;
        const float s15 = 3.8729833462074170f;
        const float s15h = 1.9364916731037085f;
        am0 += m0;
        am1 = fmaf(m1, s3 * ux, am1);
        am2_ = fmaf(m1, s3 * uy, am2_);
        am3 = fmaf(m1, s3 * uz, am3);
        am4 = fmaf(m2, s15 * ux * uy, am4);
        am5 = fmaf(m2, s15 * uy * uz, am5);
        am6 = fmaf(m2, s5h * (3.0f * uz * uz - 1.0f), am6);
        am7 = fmaf(m2, s15 * ux * uz, am7);
        am8 = fmaf(m2, s15h * (ux * ux - uy * uy), am8);
    }

    // A[n][f][s] / AVG_NEIGH -> LDS transpose (f-major rows, float4 loads)
    const float inv16 = 0.0625f;
    *(float4*)&At[g * 12]     = make_float4(am0 * inv16, am1 * inv16, am2_ * inv16, am3 * inv16);
    *(float4*)&At[g * 12 + 4] = make_float4(am4 * inv16, am5 * inv16, am6 * inv16, am7 * inv16);
    At[g * 12 + 8] = am8 * inv16;
    __syncthreads();

    // mixing: out[g][s] = sum_f A[f][s] * Wmix[l(s)][f][g]
    float b0 = 0.f, b1 = 0.f, b2 = 0.f, b3 = 0.f, b4 = 0.f,
          b5 = 0.f, b6 = 0.f, b7 = 0.f, b8 = 0.f;
    for (int f = 0; f < 64; f++) {
        float w0 = Wmixt[f * 64 + g];
        float w1 = Wmixt[4096 + f * 64 + g];
        float w2 = Wmixt[8192 + f * 64 + g];
        float4 aA = *(const float4*)&At[f * 12];       // broadcast reads
        float4 aB = *(const float4*)&At[f * 12 + 4];
        float a8 = At[f * 12 + 8];
        b0 = fmaf(aA.x, w0, b0);
        b1 = fmaf(aA.y, w1, b1);
        b2 = fmaf(aA.z, w1, b2);
        b3 = fmaf(aA.w, w1, b3);
        b4 = fmaf(aB.x, w2, b4);
        b5 = fmaf(aB.y, w2, b5);
        b6 = fmaf(aB.z, w2, b6);
        b7 = fmaf(aB.w, w2, b7);
        b8 = fmaf(a8, w2, b8);
    }

    // species-conditioned polynomial scale
    float wp0 = 0.f, wp1 = 0.f, wp2 = 0.f;
    #pragma unroll
    for (int e = 0; e < NE; e++) {
        float a = node_attrs[n * NE + e];
        const float* W = Wprodt + (e * F + g) * 3;
        wp0 = fmaf(a, W[0], wp0);
        wp1 = fmaf(a, W[1], wp1);
        wp2 = fmaf(a, W[2], wp2);
    }
    float p1 = b0;
    float p2 = b0 * b0 + b1 * b1 + b2 * b2 + b3 * b3 + b4 * b4 +
               b5 * b5 + b6 * b6 + b7 * b7 + b8 * b8;
    float scale = wp0 + wp1 * p1 + wp2 * p2;
    float sc0 = b0 * scale;
    int b = batch[n];

    if (PHASE == 0) {
        Sout[(size_t)n * F + g] = sc0;
        float v = sc0 * Wread0[g];
        #pragma unroll
        for (int off = 32; off > 0; off >>= 1) v += __shfl_xor(v, off);
        if (g == 0) atomicAdd(&epart[b * EPW + (n & (EPW - 1))], v);
    } else {
        sc0 += Sin[(size_t)n * F + g];   // residual (prev channel-0)
        scs[g] = sc0;
        __syncthreads();
        float v = 0.0f;
        if (g < 16) {
            float acc = 0.0f;
            for (int k = 0; k < 64; k++)
                acc = fmaf(scs[k], Wm1[k * 16 + g], acc);
            v = silu(acc) * wm2[g];
        }
        #pragma unroll
        for (int off = 32; off > 0; off >>= 1) v += __shfl_xor(v, off);
        if (g == 0) atomicAdd(&epart[b * EPW + (n & (EPW - 1))], v);
    }
}

// ---------------------------------------------------------------------------
// Kernel 6: final energy reduction; sole writer of d_out.
// ---------------------------------------------------------------------------
__global__ __launch_bounds__(256) void reduce_energy(
    const float* __restrict__ epart, float* __restrict__ out)
{
    int t = threadIdx.x;
    __shared__ float ps[GSEG][4];
    for (int b = 0; b < GSEG; b++) {
        float v = epart[b * EPW + t];
        #pragma unroll
        for (int off = 32; off > 0; off >>= 1) v += __shfl_xor(v, off);
        if ((t & 63) == 0) ps[b][t >> 6] = v;
    }
    __syncthreads();
    if (t < GSEG) out[t] = ps[t][0] + ps[t][1] + ps[t][2] + ps[t][3];
}

extern "C" void kernel_launch(void* const* d_in, const int* in_sizes, int n_in,
                              void* d_out, int out_size, void* d_ws, size_t ws_size,
                              hipStream_t stream) {
    const float* positions  = (const float*)d_in[0];
    const float* node_attrs = (const float*)d_in[1];
    const float* shifts     = (const float*)d_in[2];
    // d_in[3] charges: unused (charge_density never feeds energy)
    const int*   edge_index = (const int*)d_in[4];
    const int*   batch      = (const int*)d_in[5];
    const float* AE         = (const float*)d_in[6];
    const float* W_embed    = (const float*)d_in[7];
    const float* Wr0        = (const float*)d_in[8];
    const float* Wr1        = (const float*)d_in[9];
    const float* Wr2        = (const float*)d_in[10];
    const float* Wmix       = (const float*)d_in[11];
    const float* Wprod      = (const float*)d_in[12];
    const float* Wread0     = (const float*)d_in[13];
    const float* Wm1        = (const float*)d_in[14];
    const float* wm2        = (const float*)d_in[15];
    // d_in[16] Wq: unused

    int N = in_sizes[0] / 3;
    int E = in_sizes[4] / 2;
    float* out = (float*)d_out;

    char* ws = (char*)d_ws;
    size_t off = 0;
    float4* geo   = (float4*)(ws + off); off += (size_t)E * sizeof(float4);
    float*  S0    = (float*)(ws + off);  off += (size_t)N * F * sizeof(float);
    float*  S1    = (float*)(ws + off);  off += (size_t)N * F * sizeof(float);
    int*    esrc  = (int*)(ws + off);    off += (size_t)E * sizeof(int);
    int*    edst  = (int*)(ws + off);    off += (size_t)E * sizeof(int);
    int*    perm  = (int*)(ws + off);    off += (size_t)E * sizeof(int);
    int*    deg   = (int*)(ws + off);    off += (size_t)N * sizeof(int);
    int*    start = (int*)(ws + off);    off += (size_t)N * sizeof(int);
    int*    cursor= (int*)(ws + off);    off += (size_t)N * sizeof(int);
    float*  epart = (float*)(ws + off);  off += GSEG * EPW * sizeof(float);
    int*    count = (int*)(ws + off);    off += 128;
    int*    total = (int*)(ws + off);    off += 128;

    hipMemsetAsync(deg, 0, (size_t)N * sizeof(int), stream);
    hipMemsetAsync(epart, 0, GSEG * EPW * sizeof(float) + 256, stream); // + count/total

    int nodeBlocks4 = (N + 3) / 4;
    int nodeBlocks256 = (N + 255) / 256;
    int edgeBlocks = (E + 255) / 256;

    init_nodes<<<nodeBlocks4, 256, 0, stream>>>(node_attrs, AE, W_embed, batch, S0, epart, N);
    edge_prep<<<edgeBlocks, 256, 0, stream>>>(positions, shifts, edge_index, E,
                                              count, geo, esrc, edst, deg);
    alloc_start<<<nodeBlocks256, 256, 0, stream>>>(deg, start, cursor, total, N);
    scatter_perm<<<edgeBlocks, 256, 0, stream>>>(count, edst, cursor, perm);

    // t = 0: read S0, write S1
    gather_node<0><<<N, 64, 0, stream>>>(geo, esrc, perm, start, deg,
                                         Wr0, Wr1, Wr2, Wmix, Wprod,
                                         node_attrs, batch, Wread0, Wm1, wm2,
                                         S0, S1, epart, N);
    // t = 1: read S1 (messages + residual), no Sout needed
    gather_node<1><<<N, 64, 0, stream>>>(geo, esrc, perm, start, deg,
                                         Wr0 + 512, Wr1 + 4096, Wr2 + 12288,
                                         Wmix + 12288, Wprod + NE * F * 3,
                                         node_attrs, batch, Wread0, Wm1, wm2,
                                         S1, S1, epart, N);

    reduce_energy<<<1, 256, 0, stream>>>(epart, out);
}